// Round 4
// baseline (208.568 us; speedup 1.0000x reference)
//
#include <hip/hip_runtime.h>
#include <math.h>

// Problem constants
#define NPIX    65536      // 256*256 pixels per camera
#define NBINS   64
#define NBATCH  32         // B*C = 4*8
#define SPLIT   32         // pixel-chunks per batch
#define BLOCKT  256
#define PXPT    4          // pixels per thread per iteration
#define ITERS   (NPIX / SPLIT / (BLOCKT * PXPT))   // = 2 -> 8 px/thread
#define WIN     12         // bins k0..k0+11, edges k0..k0+12 (R7 math, absmax 2.9e-11)
#define NG      (BLOCKT / 2)        // 2 lanes share one histogram
#define GSTRIDE 65                  // ODD stride: group base bank = g mod 32 (all banks)
#define LDSN    (NG * GSTRIDE + 4 * NBINS)  // hists + epilogue partials = 34.3 KB
//
// R10 THEORY: R8/R9 full-edge eval (65 rcp/px) is trans-pipe heavy (~7us/CU) and
// measured ~27us vs R0-windowed ~18us. Window was right; the two prior windowed
// failures were artifacts, both fixed here:
//  - R0 failed on LATENCY: dependent LDS b128 read->wait->write RMW chains.
//    Fix: fire-and-forget ds_add_f32 (atomicAdd, result unused) -> no lgkmcnt
//    waits anywhere in the main loop.
//  - R7 failed on BANKS: stride 72 mapped 16 group bases to 4 banks (8g mod 32)
//    + 16-way same-address serialization. Fix: stride 65 (odd -> base bank =
//    g mod 32, full coverage), share only 2 lanes/group -> worst 2-way serial.
// Floor: max(HBM 8.2us, trans 2.1, DS 2.6, VALU 1.6) -> HBM-bound.
// R6 lesson (kept): software prefetch of global loads regressed; simple loads.

#define THREE_LOG2E 4.328085122666891f

__global__ __launch_bounds__(BLOCKT, 4) void spad_hist_kernel(
    const float* __restrict__ normals,      // [32, 65536, 3]
    const float* __restrict__ inters,       // [32, 65536, 3]
    const float* __restrict__ film,         // [65536, 3]
    const float* __restrict__ cosm,         // [65536]
    float* __restrict__ ws,                 // [1024, 64] block partials
    float kconst, float lmask_c, float half_inv_bin)
{
    __shared__ float hist[LDSN];
    const int tid = threadIdx.x;
    for (int i = tid; i < LDSN; i += BLOCKT) hist[i] = 0.0f;
    __syncthreads();

    const int b = blockIdx.x & (NBATCH - 1);
    const int chunk = blockIdx.x / NBATCH;
    const int pix0 = chunk * (NPIX / SPLIT);
    float* const hg = &hist[(tid >> 1) * GSTRIDE];   // pair-shared histogram

    // E3^m, m=0..12 — independent scaling breaks the serial exp chain
    const float E3P[13] = {
        1.0f, 20.085536923187668f, 403.4287934927351f, 8103.083927575384f,
        162754.79141900392f, 3269017.372472111f, 65659969.13733051f,
        1318815734.4832146f, 26489122129.843472f, 532048240601.79865f,
        10686474581524.462f, 214643579785916.06f, 4311231547115195.0f };

    #pragma unroll
    for (int it = 0; it < ITERS; ++it) {
        const int pp = pix0 + (it * BLOCKT + tid) * PXPT;
        const float4* n4 = (const float4*)(normals + ((size_t)b * NPIX + pp) * 3);
        const float4* i4 = (const float4*)(inters  + ((size_t)b * NPIX + pp) * 3);
        const float4* f4 = (const float4*)(film + (size_t)pp * 3);
        const float4  c4 = *(const float4*)(cosm + pp);
        float4 n0 = n4[0], n1 = n4[1], n2 = n4[2];
        float4 i0 = i4[0], i1 = i4[1], i2 = i4[2];
        float4 f0 = f4[0], f1 = f4[1], f2 = f4[2];

        // gather 4 pixels into arrays (SoA in registers)
        float NX[4] = {n0.x, n0.w, n1.z, n2.y}, NY[4] = {n0.y, n1.x, n1.w, n2.z},
              NZ[4] = {n0.z, n1.y, n2.x, n2.w};
        float IX[4] = {i0.x, i0.w, i1.z, i2.y}, IY[4] = {i0.y, i1.x, i1.w, i2.z},
              IZ[4] = {i0.z, i1.y, i2.x, i2.w};
        float FX[4] = {f0.x, f0.w, f1.z, f2.y}, FY[4] = {f0.y, f1.x, f1.w, f2.z},
              FZ[4] = {f0.z, f1.y, f2.x, f2.w};
        float CM[4] = {c4.x, c4.y, c4.z, c4.w};

        #pragma unroll
        for (int p = 0; p < 4; ++p) {
            float dt = FX[p] * NX[p] + FY[p] * NY[p] + FZ[p] * NZ[p];
            dt = fminf(fmaxf(dt, 0.0f), 1.0f);
            float lx = IX[p] - 0.002f;
            float lxy2 = lx * lx + IY[p] * IY[p];
            float l2 = lxy2 + IZ[p] * IZ[p];
            float ldst = __builtin_amdgcn_sqrtf(l2);
            float lm = __builtin_amdgcn_exp2f(
                lmask_c * lxy2 * __builtin_amdgcn_rcpf(IZ[p] * IZ[p]));
            float cm3 = CM[p] * CM[p] * CM[p];
            float r = dt * lm * kconst * cm3 * __builtin_amdgcn_rcpf(l2);
            float di = __builtin_amdgcn_sqrtf(
                IX[p] * IX[p] + IY[p] * IY[p] + IZ[p] * IZ[p]);
            float d = (di + ldst) * half_inv_bin;   // depth in bin units

            int j0 = (int)floorf(d);
            j0 = j0 < 5 ? 5 : (j0 > 57 ? 57 : j0);
            const int k0 = j0 - 5;                  // window start, in [0, 52]
            float e0 = __builtin_amdgcn_exp2f(((float)k0 - d) * THREE_LOG2E);
            float S[WIN + 1];
            #pragma unroll
            for (int m = 0; m < WIN + 1; ++m)       // 13 independent fma+rcp
                S[m] = __builtin_amdgcn_rcpf(fmaf(e0, E3P[m], 1.0f));

            // fire-and-forget ds_add_f32: no lgkmcnt waits, offset:4m folded
            float* hp = hg + k0;
            #pragma unroll
            for (int m = 0; m < WIN; ++m)
                atomicAdd(&hp[m], r * (S[m] - S[m + 1]));
        }
    }
    __syncthreads();

    // epilogue: reduce 128 pair-histograms -> 64-bin block partial.
    // step 1: thread (q = tid>>6, k = tid&63) sums groups q*32..q*32+31 at bin k
    {
        const int k = tid & 63, q = tid >> 6;
        float s = 0.0f;
        #pragma unroll
        for (int g = 0; g < NG / 4; ++g)
            s += hist[(q * (NG / 4) + g) * GSTRIDE + k];
        hist[NG * GSTRIDE + q * NBINS + k] = s;     // partials area (past hists)
    }
    __syncthreads();
    if (tid < NBINS) {
        const float* pa = &hist[NG * GSTRIDE];
        ws[(size_t)blockIdx.x * NBINS + tid] =
            pa[tid] + pa[NBINS + tid] + pa[2 * NBINS + tid] + pa[3 * NBINS + tid];
    }
}

__global__ __launch_bounds__(256) void spad_reduce_kernel(
    const float* __restrict__ ws, float* __restrict__ out)
{
    const int o = blockIdx.x * 256 + threadIdx.x;  // 0..2047 -> (b, k)
    const int b = o >> 6;
    const int k = o & 63;
    float s = 0.0f;
    #pragma unroll
    for (int c = 0; c < SPLIT; ++c)
        s += ws[((size_t)(c * NBATCH + b)) * NBINS + k];
    out[o] = s;   // every element written -> no memset needed
}

extern "C" void kernel_launch(void* const* d_in, const int* in_sizes, int n_in,
                              void* d_out, int out_size, void* d_ws, size_t ws_size,
                              hipStream_t stream) {
    const float* normals = (const float*)d_in[0];
    const float* inters  = (const float*)d_in[1];
    const float* film    = (const float*)d_in[2];
    const float* cosm    = (const float*)d_in[3];
    float* out = (float*)d_out;
    float* ws  = (float*)d_ws;   // needs 1024*64*4 = 256 KiB

    // host-side double-precision constants (argument setup; capture-safe)
    const double fov_rad = 33.0 * M_PI / 180.0;
    const double width = 2.0 * tan(fov_rad / 2.0);
    const double kconst_d = width * width / M_PI / 65536.0;       // width^2/pi/R^2
    const double sig = tan(21.5 * M_PI / 180.0) / 1.4;
    const double log2e = 1.4426950408889634;
    const double lmask_c_d = -log2e / (2.0 * sig * sig);          // exp2 scale
    const double half_inv_bin_d = 0.5 / 0.0136;

    spad_hist_kernel<<<NBATCH * SPLIT, BLOCKT, 0, stream>>>(
        normals, inters, film, cosm, ws,
        (float)kconst_d, (float)lmask_c_d, (float)half_inv_bin_d);

    spad_reduce_kernel<<<(NBATCH * NBINS) / 256, 256, 0, stream>>>(ws, out);
}